// Round 1
// baseline (1608.618 us; speedup 1.0000x reference)
//
#include <hip/hip_runtime.h>
#include <hip/hip_bf16.h>
#include <cstdint>
#include <cstddef>

// ---------------------------------------------------------------------------
// GraphSAGE 2-layer forward (mean aggregator), MI355X / gfx950.
//
// reference:
//   h  = relu(x @ Ws1.T + (segsum(x[src1],dst1)/deg1) @ Wn1.T + b1)
//   out = h @ Ws2.T + (segsum(h[src2],dst2)/deg2) @ Wn2.T + b2
//
// Restructure (linearity of segment_sum):
//   layer1: aggregate x in 128-dim, then one fused GEMM with K-concat:
//           h = relu([x | xn] @ [Ws1;Wn1].T + b1)           (M=N, N=256, K=256)
//   layer2: project FIRST, aggregate the 40-dim projections:
//           s = h @ Ws2.T ; p = h @ Wn2.T  (one GEMM, 80 cols)
//           out = s + segsum(p[src2],dst2)/deg2 + b2
// ---------------------------------------------------------------------------

#define D_IN 128
#define D_H  256
#define D_C  40

typedef __bf16 bf16_t;
typedef __attribute__((ext_vector_type(8))) __bf16 bf16x8;
typedef __attribute__((ext_vector_type(4))) float    f32x4;

// ---------------- ws layout (bytes) ----------------
// [agg1  N*128*4][deg1 N*4][agg2 N*40*4][deg2 N*4]   <- zeroed each call
// [hb    N*256*2][p N*40*4][w1b 256*256*2][w2b 80*256*2]
static constexpr size_t NMAX      = 100000;
static constexpr size_t AGG1_OFF  = 0;
static constexpr size_t AGG1_SZ   = NMAX * 128 * 4;
static constexpr size_t DEG1_OFF  = AGG1_OFF + AGG1_SZ;
static constexpr size_t DEG1_SZ   = NMAX * 4;
static constexpr size_t AGG2_OFF  = DEG1_OFF + DEG1_SZ;
static constexpr size_t AGG2_SZ   = NMAX * 40 * 4;
static constexpr size_t DEG2_OFF  = AGG2_OFF + AGG2_SZ;
static constexpr size_t DEG2_SZ   = NMAX * 4;
static constexpr size_t ZERO_BYTES = DEG2_OFF + DEG2_SZ - AGG1_OFF;
static constexpr size_t HB_OFF    = DEG2_OFF + DEG2_SZ;
static constexpr size_t HB_SZ     = NMAX * 256 * 2;
static constexpr size_t P_OFF     = HB_OFF + HB_SZ;
static constexpr size_t P_SZ      = NMAX * 40 * 4;
static constexpr size_t W1B_OFF   = P_OFF + P_SZ;
static constexpr size_t W1B_SZ    = 256 * 256 * 2;
static constexpr size_t W2B_OFF   = W1B_OFF + W1B_SZ;
static constexpr size_t W2B_SZ    = 80 * 256 * 2;
static constexpr size_t WS_NEEDED = W2B_OFF + W2B_SZ;

// ---------------- weight convert: fp32 -> bf16, K/col concat ----------------
__global__ void k_conv_w(const float* __restrict__ ws1, const float* __restrict__ wn1,
                         const float* __restrict__ ws2, const float* __restrict__ wn2,
                         bf16_t* __restrict__ w1b, bf16_t* __restrict__ w2b) {
  int t = blockIdx.x * 256 + threadIdx.x;
  if (t < 256 * 256) {               // w1b[col][k], k<128 -> Ws1, k>=128 -> Wn1
    int col = t >> 8, k = t & 255;
    float v = (k < 128) ? ws1[col * 128 + k] : wn1[col * 128 + (k - 128)];
    w1b[t] = (bf16_t)v;
  }
  if (t < 80 * 256) {                // w2b[col][k], col<40 -> Ws2, col>=40 -> Wn2
    int col = t >> 8, k = t & 255;
    float v = (col < 40) ? ws2[col * 256 + k] : wn2[(col - 40) * 256 + k];
    w2b[t] = (bf16_t)v;
  }
}

// ---------------- degree counts (both layers in one pass) ----------------
__global__ void k_deg(const int* __restrict__ dst1, const int* __restrict__ dst2,
                      float* __restrict__ deg1, float* __restrict__ deg2, int E) {
  int e = blockIdx.x * 256 + threadIdx.x;
  if (e < E) {
    atomicAdd(&deg1[dst1[e]], 1.0f);
    atomicAdd(&deg2[dst2[e]], 1.0f);
  }
}

// ---------------- scatter layer1: agg1[dst] += x[src] (128 f32) ----------------
__global__ void k_scatter1(const float* __restrict__ x, const int* __restrict__ src,
                           const int* __restrict__ dst, float* __restrict__ agg1, int E) {
  long long t = (long long)blockIdx.x * 256 + threadIdx.x;  // t = e*32 + j
  int e = (int)(t >> 5), j = (int)(t & 31);
  if (e < E) {
    int s = src[e], d = dst[e];
    float4 v = ((const float4*)(x + (size_t)s * 128))[j];
    float* o = agg1 + (size_t)d * 128 + j * 4;
    atomicAdd(o + 0, v.x);
    atomicAdd(o + 1, v.y);
    atomicAdd(o + 2, v.z);
    atomicAdd(o + 3, v.w);
  }
}

// ---------------- GEMM1: h = relu([x | agg1/deg] @ w1b.T + b1) -> bf16 ----------------
// block = 256 thr (4 waves). Block tile: 64 rows x 256 cols. Wave: 64 rows x 64 cols.
// mfma_f32_16x16x32_bf16; A frags converted f32->bf16 at load.
__global__ void k_gemm1(const float* __restrict__ x, const float* __restrict__ agg1,
                        const float* __restrict__ deg1, const bf16_t* __restrict__ w1b,
                        const float* __restrict__ b1, bf16_t* __restrict__ hb, int N) {
  const int m0   = blockIdx.x * 64;
  const int wv   = threadIdx.x >> 6;
  const int lane = threadIdx.x & 63;
  const int lr   = lane & 15;   // fragment row (A) / col (B,C)
  const int lg   = lane >> 4;   // k-subgroup
  const int c0   = wv * 64;

  f32x4 acc[4][4] = {};

  int   rows[4];
  float rdeg[4];
#pragma unroll
  for (int m = 0; m < 4; ++m) {
    int r = m0 + m * 16 + lr;
    rows[m] = (r < N) ? r : 0;
    rdeg[m] = 1.0f / fmaxf(deg1[rows[m]], 1.0f);
  }

#pragma unroll
  for (int ks = 0; ks < 8; ++ks) {
    const int kk = (ks & 3) * 32 + lg * 8;  // k within the 128-wide half
    bf16x8 a[4];
#pragma unroll
    for (int m = 0; m < 4; ++m) {
      const float* srcp = ((ks < 4) ? x : agg1) + (size_t)rows[m] * 128 + kk;
      float4 v0 = ((const float4*)srcp)[0];
      float4 v1 = ((const float4*)srcp)[1];
      float  sc = (ks < 4) ? 1.0f : rdeg[m];
      a[m][0] = (bf16_t)(v0.x * sc);
      a[m][1] = (bf16_t)(v0.y * sc);
      a[m][2] = (bf16_t)(v0.z * sc);
      a[m][3] = (bf16_t)(v0.w * sc);
      a[m][4] = (bf16_t)(v1.x * sc);
      a[m][5] = (bf16_t)(v1.y * sc);
      a[m][6] = (bf16_t)(v1.z * sc);
      a[m][7] = (bf16_t)(v1.w * sc);
    }
    bf16x8 b[4];
#pragma unroll
    for (int bn = 0; bn < 4; ++bn) {
      int col = c0 + bn * 16 + lr;
      b[bn] = *(const bf16x8*)(w1b + (size_t)col * 256 + ks * 32 + lg * 8);
    }
#pragma unroll
    for (int m = 0; m < 4; ++m)
#pragma unroll
      for (int bn = 0; bn < 4; ++bn)
        acc[m][bn] = __builtin_amdgcn_mfma_f32_16x16x32_bf16(a[m], b[bn], acc[m][bn], 0, 0, 0);
  }

  // epilogue: C/D layout col = lane&15, row = (lane>>4)*4 + i  [m89-verified]
#pragma unroll
  for (int bn = 0; bn < 4; ++bn) {
    int   col  = c0 + bn * 16 + lr;
    float bias = b1[col];
#pragma unroll
    for (int m = 0; m < 4; ++m) {
#pragma unroll
      for (int i = 0; i < 4; ++i) {
        int r = m0 + m * 16 + lg * 4 + i;
        if (r < N) {
          float v = acc[m][bn][i] + bias;
          hb[(size_t)r * 256 + col] = (bf16_t)fmaxf(v, 0.0f);
        }
      }
    }
  }
}

// ---------------- GEMM2: [s | p] = hb @ w2b.T  (80 cols) ----------------
// block = 256 thr (4 waves). Block tile: 128 rows. Wave: 32 rows x 80 cols.
__global__ void k_gemm2(const bf16_t* __restrict__ hb, const bf16_t* __restrict__ w2b,
                        float* __restrict__ s_out, float* __restrict__ p_out, int N) {
  const int wv   = threadIdx.x >> 6;
  const int m0   = blockIdx.x * 128 + wv * 32;
  const int lane = threadIdx.x & 63;
  const int lr   = lane & 15;
  const int lg   = lane >> 4;

  f32x4 acc[2][5] = {};

  int rows[2];
#pragma unroll
  for (int m = 0; m < 2; ++m) {
    int r = m0 + m * 16 + lr;
    rows[m] = (r < N) ? r : 0;
  }

#pragma unroll
  for (int ks = 0; ks < 8; ++ks) {
    const int k = ks * 32 + lg * 8;
    bf16x8 a[2];
#pragma unroll
    for (int m = 0; m < 2; ++m)
      a[m] = *(const bf16x8*)(hb + (size_t)rows[m] * 256 + k);
    bf16x8 b[5];
#pragma unroll
    for (int bn = 0; bn < 5; ++bn) {
      int col = bn * 16 + lr;
      b[bn] = *(const bf16x8*)(w2b + (size_t)col * 256 + k);
    }
#pragma unroll
    for (int m = 0; m < 2; ++m)
#pragma unroll
      for (int bn = 0; bn < 5; ++bn)
        acc[m][bn] = __builtin_amdgcn_mfma_f32_16x16x32_bf16(a[m], b[bn], acc[m][bn], 0, 0, 0);
  }

#pragma unroll
  for (int bn = 0; bn < 5; ++bn) {
    int col = bn * 16 + lr;
#pragma unroll
    for (int m = 0; m < 2; ++m) {
#pragma unroll
      for (int i = 0; i < 4; ++i) {
        int r = m0 + m * 16 + lg * 4 + i;
        if (r < N) {
          float v = acc[m][bn][i];
          if (col < 40) s_out[(size_t)r * 40 + col] = v;
          else          p_out[(size_t)r * 40 + (col - 40)] = v;
        }
      }
    }
  }
}

// ---------------- scatter layer2: agg2[dst] += p[src] (40 f32) ----------------
__global__ void k_scatter2(const float* __restrict__ p, const int* __restrict__ src,
                           const int* __restrict__ dst, float* __restrict__ agg2, int E) {
  long long t = (long long)blockIdx.x * 256 + threadIdx.x;  // t = e*10 + j
  int e = (int)(t / 10), j = (int)(t % 10);
  if (e < E) {
    int s = src[e], d = dst[e];
    float4 v = ((const float4*)(p + (size_t)s * 40))[j];
    float* o = agg2 + (size_t)d * 40 + j * 4;
    atomicAdd(o + 0, v.x);
    atomicAdd(o + 1, v.y);
    atomicAdd(o + 2, v.z);
    atomicAdd(o + 3, v.w);
  }
}

// ---------------- final: out = s + agg2/deg2 + b2 ----------------
__global__ void k_final(float* __restrict__ out, const float* __restrict__ agg2,
                        const float* __restrict__ deg2, const float* __restrict__ b2, int N) {
  int t = blockIdx.x * 256 + threadIdx.x;
  if (t < N * 40) {
    int n = t / 40, c = t % 40;
    float dg = fmaxf(deg2[n], 1.0f);
    out[t] = out[t] + agg2[t] / dg + b2[c];
  }
}

extern "C" void kernel_launch(void* const* d_in, const int* in_sizes, int n_in,
                              void* d_out, int out_size, void* d_ws, size_t ws_size,
                              hipStream_t stream) {
  const float* x    = (const float*)d_in[0];
  const int*   src1 = (const int*)d_in[1];
  const int*   dst1 = (const int*)d_in[2];
  const int*   src2 = (const int*)d_in[3];
  const int*   dst2 = (const int*)d_in[4];
  const float* ws1  = (const float*)d_in[5];
  const float* wn1  = (const float*)d_in[6];
  const float* b1   = (const float*)d_in[7];
  const float* ws2  = (const float*)d_in[8];
  const float* wn2  = (const float*)d_in[9];
  const float* b2   = (const float*)d_in[10];
  float*       out  = (float*)d_out;

  const int N = in_sizes[0] / D_IN;
  const int E = in_sizes[1];
  if (ws_size < WS_NEEDED) return;  // clean failure rather than OOB

  char*   ws   = (char*)d_ws;
  float*  agg1 = (float*)(ws + AGG1_OFF);
  float*  deg1 = (float*)(ws + DEG1_OFF);
  float*  agg2 = (float*)(ws + AGG2_OFF);
  float*  deg2 = (float*)(ws + DEG2_OFF);
  bf16_t* hb   = (bf16_t*)(ws + HB_OFF);
  float*  p    = (float*)(ws + P_OFF);
  bf16_t* w1b  = (bf16_t*)(ws + W1B_OFF);
  bf16_t* w2b  = (bf16_t*)(ws + W2B_OFF);

  // zero the accumulators (agg1|deg1|agg2|deg2 are contiguous)
  hipMemsetAsync(ws + AGG1_OFF, 0, ZERO_BYTES, stream);

  k_conv_w<<<256, 256, 0, stream>>>(ws1, wn1, ws2, wn2, w1b, w2b);
  k_deg<<<(E + 255) / 256, 256, 0, stream>>>(dst1, dst2, deg1, deg2, E);

  {
    long long tot = (long long)E * 32;
    k_scatter1<<<(int)((tot + 255) / 256), 256, 0, stream>>>(x, src1, dst1, agg1, E);
  }

  k_gemm1<<<(N + 63) / 64, 256, 0, stream>>>(x, agg1, deg1, w1b, b1, hb, N);
  k_gemm2<<<(N + 127) / 128, 256, 0, stream>>>(hb, w2b, out, p, N);

  {
    long long tot = (long long)E * 10;
    k_scatter2<<<(int)((tot + 255) / 256), 256, 0, stream>>>(p, src2, dst2, agg2, E);
  }

  k_final<<<(N * 40 + 255) / 256, 256, 0, stream>>>(out, agg2, deg2, b2, N);
}

// Round 2
// 350.382 us; speedup vs baseline: 4.5910x; 4.5910x over previous
//
#include <hip/hip_runtime.h>
#include <hip/hip_bf16.h>
#include <cstdint>
#include <cstddef>

// ---------------------------------------------------------------------------
// GraphSAGE 2-layer forward (mean aggregator), MI355X / gfx950.
//
//   h  = relu(x @ Ws1.T + mean_nbr1(x) @ Wn1.T + b1)
//   out = h @ Ws2.T + mean_nbr2(h) @ Wn2.T + b2
//
// Restructure:
//   layer1: aggregate x in 128-dim (CSR gather, no atomics), fused K-concat
//           GEMM: h = relu([x | mean1(x)] @ [Ws1;Wn1].T + b1)
//   layer2: project FIRST (linearity): [s|p] = h @ [Ws2;Wn2].T, then gather
//           40-dim p:  out = s + mean2(p) + b2
//
// Round-1 lesson: scatter-with-fp32-atomics was atomic-bound (1009us, 17% BW,
// 1.2GB L2 writeback). CSR gather eliminates all fp32 atomics.
// ---------------------------------------------------------------------------

#define D_IN 128
#define D_H  256
#define D_C  40

typedef __bf16 bf16_t;
typedef __attribute__((ext_vector_type(8))) __bf16 bf16x8;
typedef __attribute__((ext_vector_type(4))) __bf16 bf16x4;
typedef __attribute__((ext_vector_type(4))) float  f32x4;

// ---------------- ws layout (bytes), all offsets 256B-aligned ----------------
static constexpr size_t NMAX = 100000;
static constexpr size_t EMAX = 600000;
static constexpr size_t alignup(size_t v) { return (v + 255) & ~size_t(255); }

static constexpr size_t CUR1_OFF = 0;                                    // int[N]   (counts, then cursors)
static constexpr size_t CUR2_OFF = alignup(CUR1_OFF + NMAX * 4);         // int[N]
static constexpr size_t ZERO_BYTES = CUR2_OFF + NMAX * 4;                // zero cur1|cur2
static constexpr size_t RP1_OFF  = alignup(CUR2_OFF + NMAX * 4);         // int[N+1]
static constexpr size_t RP2_OFF  = alignup(RP1_OFF + (NMAX + 1) * 4);    // int[N+1]
static constexpr size_t BS1_OFF  = alignup(RP2_OFF + (NMAX + 1) * 4);    // int[512]
static constexpr size_t BS2_OFF  = alignup(BS1_OFF + 512 * 4);           // int[512]
static constexpr size_t CSR1_OFF = alignup(BS2_OFF + 512 * 4);           // int[E]
static constexpr size_t CSR2_OFF = alignup(CSR1_OFF + EMAX * 4);         // int[E]
static constexpr size_t XNB_OFF  = alignup(CSR2_OFF + EMAX * 4);         // bf16[N][128] (mean1)
static constexpr size_t HB_OFF   = alignup(XNB_OFF + NMAX * 128 * 2);    // bf16[N][256]
static constexpr size_t P_OFF    = alignup(HB_OFF + NMAX * 256 * 2);     // f32[N][40]
static constexpr size_t W1B_OFF  = alignup(P_OFF + NMAX * 40 * 4);       // bf16[256][256]
static constexpr size_t W2B_OFF  = alignup(W1B_OFF + 256 * 256 * 2);     // bf16[80][256]
static constexpr size_t WS_NEEDED = W2B_OFF + 80 * 256 * 2;

// ---------------- weight convert: fp32 -> bf16, K/col concat ----------------
__global__ void k_conv_w(const float* __restrict__ ws1, const float* __restrict__ wn1,
                         const float* __restrict__ ws2, const float* __restrict__ wn2,
                         bf16_t* __restrict__ w1b, bf16_t* __restrict__ w2b) {
  int t = blockIdx.x * 256 + threadIdx.x;
  if (t < 256 * 256) {               // w1b[col][k], k<128 -> Ws1, k>=128 -> Wn1
    int col = t >> 8, k = t & 255;
    float v = (k < 128) ? ws1[col * 128 + k] : wn1[col * 128 + (k - 128)];
    w1b[t] = (bf16_t)v;
  }
  if (t < 80 * 256) {                // w2b[col][k], col<40 -> Ws2, col>=40 -> Wn2
    int col = t >> 8, k = t & 255;
    float v = (col < 40) ? ws2[col * 256 + k] : wn2[(col - 40) * 256 + k];
    w2b[t] = (bf16_t)v;
  }
}

// ---------------- CSR build ----------------
__global__ void k_count(const int* __restrict__ dst1, const int* __restrict__ dst2,
                        int* __restrict__ cnt1, int* __restrict__ cnt2, int E) {
  int e = blockIdx.x * 256 + threadIdx.x;
  if (e < E) {
    atomicAdd(&cnt1[dst1[e]], 1);
    atomicAdd(&cnt2[dst2[e]], 1);
  }
}

// per-block exclusive scan (Hillis-Steele in LDS) + block sums
__global__ void k_scan_block(const int* __restrict__ cnt, int* __restrict__ scanned,
                             int* __restrict__ bsum, int n) {
  __shared__ int lds[256];
  int t = threadIdx.x, i = blockIdx.x * 256 + t;
  int v = (i < n) ? cnt[i] : 0;
  lds[t] = v;
  __syncthreads();
  for (int off = 1; off < 256; off <<= 1) {
    int add = (t >= off) ? lds[t - off] : 0;
    __syncthreads();
    lds[t] += add;
    __syncthreads();
  }
  if (i < n) scanned[i] = lds[t] - v;           // exclusive
  if (t == 255) bsum[blockIdx.x] = lds[255];    // block total
}

// single-block exclusive scan of block sums (nb <= 512)
__global__ void k_scan_sums(int* __restrict__ bsum, int nb) {
  __shared__ int lds[512];
  int t = threadIdx.x;
  int v = (t < nb) ? bsum[t] : 0;
  lds[t] = v;
  __syncthreads();
  for (int off = 1; off < 512; off <<= 1) {
    int add = (t >= off) ? lds[t - off] : 0;
    __syncthreads();
    lds[t] += add;
    __syncthreads();
  }
  if (t < nb) bsum[t] = lds[t] - v;             // exclusive
}

__global__ void k_add(int* __restrict__ rowptr, const int* __restrict__ bsum,
                      int n, int E) {
  int i = blockIdx.x * 256 + threadIdx.x;
  if (i < n) rowptr[i] += bsum[i >> 8];
  else if (i == n) rowptr[n] = E;
}

__global__ void k_copycur(const int* __restrict__ r1, const int* __restrict__ r2,
                          int* __restrict__ c1, int* __restrict__ c2, int n) {
  int i = blockIdx.x * 256 + threadIdx.x;
  if (i < n) { c1[i] = r1[i]; c2[i] = r2[i]; }
}

__global__ void k_fill(const int* __restrict__ s1, const int* __restrict__ d1,
                       const int* __restrict__ s2, const int* __restrict__ d2,
                       int* __restrict__ cur1, int* __restrict__ cur2,
                       int* __restrict__ csr1, int* __restrict__ csr2, int E) {
  int e = blockIdx.x * 256 + threadIdx.x;
  if (e < E) {
    csr1[atomicAdd(&cur1[d1[e]], 1)] = s1[e];
    csr2[atomicAdd(&cur2[d2[e]], 1)] = s2[e];
  }
}

// ---------------- layer-1 aggregation: xnb[n] = mean(x[nbrs]) as bf16 ----------------
// 32 lanes per node, float4 per lane (32*4 = 128). 8 nodes per 256-thr block.
__global__ void k_agg1(const float* __restrict__ x, const int* __restrict__ rowptr,
                       const int* __restrict__ csr, bf16_t* __restrict__ xnb, int N) {
  int node = (blockIdx.x * 256 + threadIdx.x) >> 5;
  int l = threadIdx.x & 31;
  if (node >= N) return;
  int beg = rowptr[node], end = rowptr[node + 1];
  float4 acc = {0.f, 0.f, 0.f, 0.f};
  for (int e = beg; e < end; ++e) {
    int s = csr[e];
    float4 v = *(const float4*)(x + (size_t)s * 128 + l * 4);
    acc.x += v.x; acc.y += v.y; acc.z += v.z; acc.w += v.w;
  }
  float rd = (end > beg) ? 1.0f / (float)(end - beg) : 0.0f;  // deg=0 -> mean 0
  bf16x4 o;
  o[0] = (bf16_t)(acc.x * rd); o[1] = (bf16_t)(acc.y * rd);
  o[2] = (bf16_t)(acc.z * rd); o[3] = (bf16_t)(acc.w * rd);
  *(bf16x4*)(xnb + (size_t)node * 128 + l * 4) = o;
}

// ---------------- GEMM1: h = relu([x | xnb] @ w1b.T + b1) -> bf16 ----------------
// block = 256 thr (4 waves). Block tile: 64 rows x 256 cols. Wave: 64 rows x 64 cols.
__global__ void k_gemm1(const float* __restrict__ x, const bf16_t* __restrict__ xnb,
                        const bf16_t* __restrict__ w1b, const float* __restrict__ b1,
                        bf16_t* __restrict__ hb, int N) {
  const int m0   = blockIdx.x * 64;
  const int wv   = threadIdx.x >> 6;
  const int lane = threadIdx.x & 63;
  const int lr   = lane & 15;   // fragment row (A) / col (B,C)
  const int lg   = lane >> 4;   // k-subgroup
  const int c0   = wv * 64;

  f32x4 acc[4][4] = {};

  int rows[4];
#pragma unroll
  for (int m = 0; m < 4; ++m) {
    int r = m0 + m * 16 + lr;
    rows[m] = (r < N) ? r : 0;
  }

#pragma unroll
  for (int ks = 0; ks < 8; ++ks) {
    const int kk = (ks & 3) * 32 + lg * 8;  // k within the 128-wide half
    bf16x8 a[4];
    if (ks < 4) {
#pragma unroll
      for (int m = 0; m < 4; ++m) {
        const float* srcp = x + (size_t)rows[m] * 128 + kk;
        float4 v0 = ((const float4*)srcp)[0];
        float4 v1 = ((const float4*)srcp)[1];
        a[m][0] = (bf16_t)v0.x; a[m][1] = (bf16_t)v0.y;
        a[m][2] = (bf16_t)v0.z; a[m][3] = (bf16_t)v0.w;
        a[m][4] = (bf16_t)v1.x; a[m][5] = (bf16_t)v1.y;
        a[m][6] = (bf16_t)v1.z; a[m][7] = (bf16_t)v1.w;
      }
    } else {
#pragma unroll
      for (int m = 0; m < 4; ++m)
        a[m] = *(const bf16x8*)(xnb + (size_t)rows[m] * 128 + kk);
    }
    bf16x8 b[4];
#pragma unroll
    for (int bn = 0; bn < 4; ++bn) {
      int col = c0 + bn * 16 + lr;
      b[bn] = *(const bf16x8*)(w1b + (size_t)col * 256 + ks * 32 + lg * 8);
    }
#pragma unroll
    for (int m = 0; m < 4; ++m)
#pragma unroll
      for (int bn = 0; bn < 4; ++bn)
        acc[m][bn] = __builtin_amdgcn_mfma_f32_16x16x32_bf16(a[m], b[bn], acc[m][bn], 0, 0, 0);
  }

  // epilogue: C/D layout col = lane&15, row = (lane>>4)*4 + i
#pragma unroll
  for (int bn = 0; bn < 4; ++bn) {
    int   col  = c0 + bn * 16 + lr;
    float bias = b1[col];
#pragma unroll
    for (int m = 0; m < 4; ++m) {
#pragma unroll
      for (int i = 0; i < 4; ++i) {
        int r = m0 + m * 16 + lg * 4 + i;
        if (r < N) {
          float v = acc[m][bn][i] + bias;
          hb[(size_t)r * 256 + col] = (bf16_t)fmaxf(v, 0.0f);
        }
      }
    }
  }
}

// ---------------- GEMM2: [s | p] = hb @ w2b.T  (80 cols) ----------------
__global__ void k_gemm2(const bf16_t* __restrict__ hb, const bf16_t* __restrict__ w2b,
                        float* __restrict__ s_out, float* __restrict__ p_out, int N) {
  const int wv   = threadIdx.x >> 6;
  const int m0   = blockIdx.x * 128 + wv * 32;
  const int lane = threadIdx.x & 63;
  const int lr   = lane & 15;
  const int lg   = lane >> 4;

  f32x4 acc[2][5] = {};

  int rows[2];
#pragma unroll
  for (int m = 0; m < 2; ++m) {
    int r = m0 + m * 16 + lr;
    rows[m] = (r < N) ? r : 0;
  }

#pragma unroll
  for (int ks = 0; ks < 8; ++ks) {
    const int k = ks * 32 + lg * 8;
    bf16x8 a[2];
#pragma unroll
    for (int m = 0; m < 2; ++m)
      a[m] = *(const bf16x8*)(hb + (size_t)rows[m] * 256 + k);
    bf16x8 b[5];
#pragma unroll
    for (int bn = 0; bn < 5; ++bn) {
      int col = bn * 16 + lr;
      b[bn] = *(const bf16x8*)(w2b + (size_t)col * 256 + k);
    }
#pragma unroll
    for (int m = 0; m < 2; ++m)
#pragma unroll
      for (int bn = 0; bn < 5; ++bn)
        acc[m][bn] = __builtin_amdgcn_mfma_f32_16x16x32_bf16(a[m], b[bn], acc[m][bn], 0, 0, 0);
  }

#pragma unroll
  for (int bn = 0; bn < 5; ++bn) {
    int col = bn * 16 + lr;
#pragma unroll
    for (int m = 0; m < 2; ++m) {
#pragma unroll
      for (int i = 0; i < 4; ++i) {
        int r = m0 + m * 16 + lg * 4 + i;
        if (r < N) {
          float v = acc[m][bn][i];
          if (col < 40) s_out[(size_t)r * 40 + col] = v;
          else          p_out[(size_t)r * 40 + (col - 40)] = v;
        }
      }
    }
  }
}

// ---------------- layer-2 aggregation fused epilogue ----------------
// out[n] = s[n] (already in out) + mean2(p)[n] + b2.  16 lanes/node, l<10 do float4.
__global__ void k_agg2fin(const float* __restrict__ p, const int* __restrict__ rowptr,
                          const int* __restrict__ csr, float* __restrict__ out,
                          const float* __restrict__ b2, int N) {
  int node = (blockIdx.x * 256 + threadIdx.x) >> 4;
  int l = threadIdx.x & 15;
  if (node >= N || l >= 10) return;
  int beg = rowptr[node], end = rowptr[node + 1];
  float4 acc = {0.f, 0.f, 0.f, 0.f};
  for (int e = beg; e < end; ++e) {
    int s = csr[e];
    float4 v = *(const float4*)(p + (size_t)s * 40 + l * 4);
    acc.x += v.x; acc.y += v.y; acc.z += v.z; acc.w += v.w;
  }
  float rd = (end > beg) ? 1.0f / (float)(end - beg) : 0.0f;
  float4 bb = *(const float4*)(b2 + l * 4);
  float* o = out + (size_t)node * 40 + l * 4;
  float4 cur = *(const float4*)o;
  cur.x += acc.x * rd + bb.x;
  cur.y += acc.y * rd + bb.y;
  cur.z += acc.z * rd + bb.z;
  cur.w += acc.w * rd + bb.w;
  *(float4*)o = cur;
}

extern "C" void kernel_launch(void* const* d_in, const int* in_sizes, int n_in,
                              void* d_out, int out_size, void* d_ws, size_t ws_size,
                              hipStream_t stream) {
  const float* x    = (const float*)d_in[0];
  const int*   src1 = (const int*)d_in[1];
  const int*   dst1 = (const int*)d_in[2];
  const int*   src2 = (const int*)d_in[3];
  const int*   dst2 = (const int*)d_in[4];
  const float* ws1  = (const float*)d_in[5];
  const float* wn1  = (const float*)d_in[6];
  const float* b1   = (const float*)d_in[7];
  const float* ws2  = (const float*)d_in[8];
  const float* wn2  = (const float*)d_in[9];
  const float* b2   = (const float*)d_in[10];
  float*       out  = (float*)d_out;

  const int N = in_sizes[0] / D_IN;
  const int E = in_sizes[1];
  if (ws_size < WS_NEEDED) return;

  char*   ws   = (char*)d_ws;
  int*    cur1 = (int*)(ws + CUR1_OFF);
  int*    cur2 = (int*)(ws + CUR2_OFF);
  int*    rp1  = (int*)(ws + RP1_OFF);
  int*    rp2  = (int*)(ws + RP2_OFF);
  int*    bs1  = (int*)(ws + BS1_OFF);
  int*    bs2  = (int*)(ws + BS2_OFF);
  int*    csr1 = (int*)(ws + CSR1_OFF);
  int*    csr2 = (int*)(ws + CSR2_OFF);
  bf16_t* xnb  = (bf16_t*)(ws + XNB_OFF);
  bf16_t* hb   = (bf16_t*)(ws + HB_OFF);
  float*  p    = (float*)(ws + P_OFF);
  bf16_t* w1b  = (bf16_t*)(ws + W1B_OFF);
  bf16_t* w2b  = (bf16_t*)(ws + W2B_OFF);

  const int nbN = (N + 255) / 256;          // 391 blocks <= 512
  const int gE  = (E + 255) / 256;

  hipMemsetAsync(ws + CUR1_OFF, 0, ZERO_BYTES, stream);   // zero counts

  k_conv_w<<<256, 256, 0, stream>>>(ws1, wn1, ws2, wn2, w1b, w2b);
  k_count<<<gE, 256, 0, stream>>>(dst1, dst2, cur1, cur2, E);

  k_scan_block<<<nbN, 256, 0, stream>>>(cur1, rp1, bs1, N);
  k_scan_block<<<nbN, 256, 0, stream>>>(cur2, rp2, bs2, N);
  k_scan_sums<<<1, 512, 0, stream>>>(bs1, nbN);
  k_scan_sums<<<1, 512, 0, stream>>>(bs2, nbN);
  k_add<<<(N + 256) / 256 + 1, 256, 0, stream>>>(rp1, bs1, N, E);
  k_add<<<(N + 256) / 256 + 1, 256, 0, stream>>>(rp2, bs2, N, E);
  k_copycur<<<nbN, 256, 0, stream>>>(rp1, rp2, cur1, cur2, N);
  k_fill<<<gE, 256, 0, stream>>>(src1, dst1, src2, dst2, cur1, cur2, csr1, csr2, E);

  k_agg1<<<(N + 7) / 8, 256, 0, stream>>>(x, rp1, csr1, xnb, N);
  k_gemm1<<<(N + 63) / 64, 256, 0, stream>>>(x, xnb, w1b, b1, hb, N);
  k_gemm2<<<(N + 127) / 128, 256, 0, stream>>>(hb, w2b, out, p, N);
  k_agg2fin<<<(N * 16 + 255) / 256, 256, 0, stream>>>(p, rp2, csr2, out, b2, N);
}

// Round 3
// 282.759 us; speedup vs baseline: 5.6890x; 1.2392x over previous
//
#include <hip/hip_runtime.h>
#include <hip/hip_bf16.h>
#include <cstdint>
#include <cstddef>

// ---------------------------------------------------------------------------
// GraphSAGE 2-layer forward (mean aggregator), MI355X / gfx950.
//
//   h  = relu(x @ Ws1.T + mean_nbr1(x) @ Wn1.T + b1)
//   out = h @ Ws2.T + mean_nbr2(h) @ Wn2.T + b2
//
// Structure (round 3):
//   xcat[N][256] = [ bf16(x) | bf16(mean1(x)) ]      (k_convx + k_agg1, CSR gather)
//   fused kernel: per 64-row tile:
//     phase A: h = relu(xcat @ w1f.T + b1)  -> LDS (bf16, padded [64][264])
//     phase B: [s|p] = h_lds @ w2f.T ; out = s + b2 ; p -> ws
//   k_agg2fin: out += mean2(p)              (CSR gather, 40-dim)
//   Weights stored FRAGMENT-MAJOR (chunk = (ks*4+lg)*NCOLS + col, 8 bf16/chunk)
//   so B-loads are wave-contiguous 256B runs, L2-resident.
//
// Round-1 lesson: fp32-atomic scatter = atomic-bound (1009us). CSR gather.
// Round-2 lesson: direct-from-global f32 A-frags + strided B + scalar bf16
//   epilogue = latency-bound GEMM (5% mfma). Fix: bf16 A, frag-major B,
//   LDS-fused h (kills the 102MB hb round-trip).
// ---------------------------------------------------------------------------

#define D_IN 128
#define D_H  256
#define D_C  40

typedef __bf16 bf16_t;
typedef __attribute__((ext_vector_type(8))) __bf16 bf16x8;
typedef __attribute__((ext_vector_type(4))) float  f32x4;

// ---------------- ws layout (bytes), 256B-aligned ----------------
static constexpr size_t NMAX = 100000;
static constexpr size_t EMAX = 600000;
static constexpr size_t alignup(size_t v) { return (v + 255) & ~size_t(255); }

static constexpr size_t CUR1_OFF = 0;                                  // int[N] counts->cursors
static constexpr size_t CUR2_OFF = alignup(CUR1_OFF + NMAX * 4);
static constexpr size_t ZERO_BYTES = CUR2_OFF + NMAX * 4;
static constexpr size_t RP1_OFF  = alignup(CUR2_OFF + NMAX * 4);       // int[N+1]
static constexpr size_t RP2_OFF  = alignup(RP1_OFF + (NMAX + 1) * 4);
static constexpr size_t BS1_OFF  = alignup(RP2_OFF + (NMAX + 1) * 4);  // int[512]
static constexpr size_t BS2_OFF  = alignup(BS1_OFF + 512 * 4);
static constexpr size_t CSR1_OFF = alignup(BS2_OFF + 512 * 4);         // int[E]
static constexpr size_t CSR2_OFF = alignup(CSR1_OFF + EMAX * 4);
static constexpr size_t XCAT_OFF = alignup(CSR2_OFF + EMAX * 4);       // bf16[N][256]
static constexpr size_t P_OFF    = alignup(XCAT_OFF + NMAX * 256 * 2); // f32[N][40]
static constexpr size_t W1F_OFF  = alignup(P_OFF + NMAX * 40 * 4);     // bf16 32*256*8
static constexpr size_t W2F_OFF  = alignup(W1F_OFF + 32 * 256 * 8 * 2);// bf16 32*80*8
static constexpr size_t WS_NEEDED = W2F_OFF + 32 * 80 * 8 * 2;

// ---------------- x -> bf16 into xcat[:,0:128] ----------------
__global__ void k_convx(const float* __restrict__ x, bf16_t* __restrict__ xcat, int N) {
  int t = blockIdx.x * 256 + threadIdx.x;
  if (t >= N * 16) return;
  int row = t >> 4, j = t & 15;
  const float* sp = x + (size_t)row * 128 + j * 8;
  float4 v0 = ((const float4*)sp)[0];
  float4 v1 = ((const float4*)sp)[1];
  bf16x8 o;
  o[0] = (bf16_t)v0.x; o[1] = (bf16_t)v0.y; o[2] = (bf16_t)v0.z; o[3] = (bf16_t)v0.w;
  o[4] = (bf16_t)v1.x; o[5] = (bf16_t)v1.y; o[6] = (bf16_t)v1.z; o[7] = (bf16_t)v1.w;
  *(bf16x8*)(xcat + (size_t)row * 256 + j * 8) = o;
}

// ---------------- weights -> bf16, fragment-major ----------------
// chunk c = (ks*4+lg)*NCOLS + col holds 8 bf16 of W[col][k0..k0+8), k0=(c_hi>>2)*32+(c_hi&3)*8
__global__ void k_conv_w(const float* __restrict__ ws1, const float* __restrict__ wn1,
                         const float* __restrict__ ws2, const float* __restrict__ wn2,
                         bf16_t* __restrict__ w1f, bf16_t* __restrict__ w2f) {
  int t = blockIdx.x * 256 + threadIdx.x;
  if (t < 32 * 256) {
    int ks4g = t >> 8, col = t & 255;
    int k0 = (ks4g >> 2) * 32 + (ks4g & 3) * 8;
    bf16x8 o;
#pragma unroll
    for (int i = 0; i < 8; ++i) {
      int k = k0 + i;   // K-concat: k<128 -> Ws1, else Wn1
      float v = (k < 128) ? ws1[col * 128 + k] : wn1[col * 128 + (k - 128)];
      o[i] = (bf16_t)v;
    }
    *(bf16x8*)(w1f + (size_t)t * 8) = o;
  }
  if (t < 32 * 80) {
    int ks4g = t / 80, col = t - ks4g * 80;
    int k0 = (ks4g >> 2) * 32 + (ks4g & 3) * 8;
    bf16x8 o;
#pragma unroll
    for (int i = 0; i < 8; ++i) {
      int k = k0 + i;   // col-concat: col<40 -> Ws2, else Wn2
      float v = (col < 40) ? ws2[col * 256 + k] : wn2[(col - 40) * 256 + k];
      o[i] = (bf16_t)v;
    }
    *(bf16x8*)(w2f + (size_t)t * 8) = o;
  }
}

// ---------------- CSR build ----------------
__global__ void k_count(const int* __restrict__ dst1, const int* __restrict__ dst2,
                        int* __restrict__ cnt1, int* __restrict__ cnt2, int E) {
  int e = blockIdx.x * 256 + threadIdx.x;
  if (e < E) {
    atomicAdd(&cnt1[dst1[e]], 1);
    atomicAdd(&cnt2[dst2[e]], 1);
  }
}

__global__ void k_scan_block(const int* __restrict__ c1, const int* __restrict__ c2,
                             int* __restrict__ r1, int* __restrict__ r2,
                             int* __restrict__ b1s, int* __restrict__ b2s, int n) {
  const int* cnt = blockIdx.y ? c2 : c1;
  int* scanned   = blockIdx.y ? r2 : r1;
  int* bsum      = blockIdx.y ? b2s : b1s;
  __shared__ int lds[256];
  int t = threadIdx.x, i = blockIdx.x * 256 + t;
  int v = (i < n) ? cnt[i] : 0;
  lds[t] = v;
  __syncthreads();
  for (int off = 1; off < 256; off <<= 1) {
    int add = (t >= off) ? lds[t - off] : 0;
    __syncthreads();
    lds[t] += add;
    __syncthreads();
  }
  if (i < n) scanned[i] = lds[t] - v;
  if (t == 255) bsum[blockIdx.x] = lds[255];
}

__global__ void k_scan_sums(int* __restrict__ b1s, int* __restrict__ b2s, int nb) {
  int* bsum = blockIdx.x ? b2s : b1s;
  __shared__ int lds[512];
  int t = threadIdx.x;
  int v = (t < nb) ? bsum[t] : 0;
  lds[t] = v;
  __syncthreads();
  for (int off = 1; off < 512; off <<= 1) {
    int add = (t >= off) ? lds[t - off] : 0;
    __syncthreads();
    lds[t] += add;
    __syncthreads();
  }
  if (t < nb) bsum[t] = lds[t] - v;
}

__global__ void k_add_cur(int* __restrict__ r1, int* __restrict__ r2,
                          const int* __restrict__ b1s, const int* __restrict__ b2s,
                          int* __restrict__ c1, int* __restrict__ c2, int n, int E) {
  int* rp       = blockIdx.y ? r2 : r1;
  const int* bs = blockIdx.y ? b2s : b1s;
  int* cur      = blockIdx.y ? c2 : c1;
  int i = blockIdx.x * 256 + threadIdx.x;
  if (i < n) {
    int v = rp[i] + bs[i >> 8];
    rp[i] = v;
    cur[i] = v;
  } else if (i == n) {
    rp[n] = E;
  }
}

__global__ void k_fill(const int* __restrict__ s1, const int* __restrict__ d1,
                       const int* __restrict__ s2, const int* __restrict__ d2,
                       int* __restrict__ cur1, int* __restrict__ cur2,
                       int* __restrict__ csr1, int* __restrict__ csr2, int E) {
  int e = blockIdx.x * 256 + threadIdx.x;
  if (e < E) {
    csr1[atomicAdd(&cur1[d1[e]], 1)] = s1[e];
    csr2[atomicAdd(&cur2[d2[e]], 1)] = s2[e];
  }
}

// ---------------- layer-1 mean -> xcat[:,128:256] (bf16 gather) ----------------
// 16 lanes/node, bf16x8 per lane (16*8 = 128 elems = one 256B row read/nbr).
__global__ void k_agg1(bf16_t* __restrict__ xcat, const int* __restrict__ rowptr,
                       const int* __restrict__ csr, int N) {
  int t = blockIdx.x * 256 + threadIdx.x;
  int node = t >> 4, l = t & 15;
  if (node >= N) return;
  int beg = rowptr[node], end = rowptr[node + 1];
  float acc[8] = {0.f, 0.f, 0.f, 0.f, 0.f, 0.f, 0.f, 0.f};
  for (int e = beg; e < end; ++e) {
    int s = csr[e];
    bf16x8 v = *(const bf16x8*)(xcat + (size_t)s * 256 + l * 8);
#pragma unroll
    for (int i = 0; i < 8; ++i) acc[i] += (float)v[i];
  }
  float rd = (end > beg) ? 1.0f / (float)(end - beg) : 0.0f;
  bf16x8 o;
#pragma unroll
  for (int i = 0; i < 8; ++i) o[i] = (bf16_t)(acc[i] * rd);
  *(bf16x8*)(xcat + (size_t)node * 256 + 128 + l * 8) = o;
}

// ---------------- fused layer1 GEMM + layer2 GEMM ----------------
// 256 thr / 4 waves. Tile: 64 rows. Phase A: 64x256 h-tile -> LDS bf16.
// Phase B: wave wv does rows [wv*16,wv*16+16) x 80 cols from LDS.
__global__ __launch_bounds__(256) void k_fused(
    const bf16_t* __restrict__ xcat, const bf16_t* __restrict__ w1f,
    const float* __restrict__ b1, const bf16_t* __restrict__ w2f,
    const float* __restrict__ b2v, float* __restrict__ out,
    float* __restrict__ p, int N) {
  __shared__ bf16_t hlds[64 * 264];   // pad 256->264 (row stride 528B = 4 banks)
  const int m0   = blockIdx.x * 64;
  const int wv   = threadIdx.x >> 6;
  const int lane = threadIdx.x & 63;
  const int lr   = lane & 15;
  const int lg   = lane >> 4;
  const int c0   = wv * 64;

  // ---- phase A: h = relu(xcat @ w1f.T + b1) ----
  f32x4 acc[4][4] = {};
  int rows[4];
#pragma unroll
  for (int m = 0; m < 4; ++m) {
    int r = m0 + m * 16 + lr;
    rows[m] = (r < N) ? r : (N - 1);
  }

#pragma unroll
  for (int ks = 0; ks < 8; ++ks) {
    const int kk = ks * 32 + lg * 8;
    bf16x8 a[4];
#pragma unroll
    for (int m = 0; m < 4; ++m)
      a[m] = *(const bf16x8*)(xcat + (size_t)rows[m] * 256 + kk);
    bf16x8 b[4];
#pragma unroll
    for (int bn = 0; bn < 4; ++bn) {
      int col = c0 + bn * 16 + lr;
      b[bn] = *(const bf16x8*)(w1f + ((size_t)(ks * 4 + lg) * 256 + col) * 8);
    }
#pragma unroll
    for (int m = 0; m < 4; ++m)
#pragma unroll
      for (int bn = 0; bn < 4; ++bn)
        acc[m][bn] = __builtin_amdgcn_mfma_f32_16x16x32_bf16(a[m], b[bn], acc[m][bn], 0, 0, 0);
  }

  // epilogue A -> LDS (C/D layout: col = lane&15, row = (lane>>4)*4 + i)
#pragma unroll
  for (int bn = 0; bn < 4; ++bn) {
    int   col  = c0 + bn * 16 + lr;
    float bias = b1[col];
#pragma unroll
    for (int m = 0; m < 4; ++m) {
#pragma unroll
      for (int i = 0; i < 4; ++i) {
        int row = m * 16 + lg * 4 + i;
        float v = acc[m][bn][i] + bias;
        hlds[row * 264 + col] = (bf16_t)fmaxf(v, 0.0f);
      }
    }
  }
  __syncthreads();

  // ---- phase B: [s|p] = h @ w2f.T ----
  f32x4 acc2[5] = {};
  const int arow = wv * 16 + lr;
#pragma unroll
  for (int ks = 0; ks < 8; ++ks) {
    const int kk = ks * 32 + lg * 8;
    bf16x8 a2 = *(const bf16x8*)(hlds + arow * 264 + kk);
#pragma unroll
    for (int bn = 0; bn < 5; ++bn) {
      int col = bn * 16 + lr;
      bf16x8 bb = *(const bf16x8*)(w2f + ((size_t)(ks * 4 + lg) * 80 + col) * 8);
      acc2[bn] = __builtin_amdgcn_mfma_f32_16x16x32_bf16(a2, bb, acc2[bn], 0, 0, 0);
    }
  }

#pragma unroll
  for (int bn = 0; bn < 5; ++bn) {
    int col = bn * 16 + lr;
#pragma unroll
    for (int i = 0; i < 4; ++i) {
      int r = m0 + wv * 16 + lg * 4 + i;
      if (r < N) {
        float v = acc2[bn][i];
        if (col < 40) out[(size_t)r * 40 + col] = v + b2v[col];
        else          p[(size_t)r * 40 + (col - 40)] = v;
      }
    }
  }
}

// ---------------- layer-2 mean fused epilogue: out += mean2(p) ----------------
// t/10 mapping: every lane active, float4 per lane (10*16B = 160B row).
__global__ void k_agg2fin(const float* __restrict__ p, const int* __restrict__ rowptr,
                          const int* __restrict__ csr, float* __restrict__ out, int N) {
  int t = blockIdx.x * 256 + threadIdx.x;
  int node = t / 10, l = t - node * 10;
  if (node >= N) return;
  int beg = rowptr[node], end = rowptr[node + 1];
  float4 acc = {0.f, 0.f, 0.f, 0.f};
  for (int e = beg; e < end; ++e) {
    int s = csr[e];
    float4 v = *(const float4*)(p + (size_t)s * 40 + l * 4);
    acc.x += v.x; acc.y += v.y; acc.z += v.z; acc.w += v.w;
  }
  float rd = (end > beg) ? 1.0f / (float)(end - beg) : 0.0f;
  float* o = out + (size_t)node * 40 + l * 4;
  float4 cur = *(const float4*)o;
  cur.x += acc.x * rd;
  cur.y += acc.y * rd;
  cur.z += acc.z * rd;
  cur.w += acc.w * rd;
  *(float4*)o = cur;
}

extern "C" void kernel_launch(void* const* d_in, const int* in_sizes, int n_in,
                              void* d_out, int out_size, void* d_ws, size_t ws_size,
                              hipStream_t stream) {
  const float* x    = (const float*)d_in[0];
  const int*   src1 = (const int*)d_in[1];
  const int*   dst1 = (const int*)d_in[2];
  const int*   src2 = (const int*)d_in[3];
  const int*   dst2 = (const int*)d_in[4];
  const float* ws1  = (const float*)d_in[5];
  const float* wn1  = (const float*)d_in[6];
  const float* b1   = (const float*)d_in[7];
  const float* ws2  = (const float*)d_in[8];
  const float* wn2  = (const float*)d_in[9];
  const float* b2   = (const float*)d_in[10];
  float*       out  = (float*)d_out;

  const int N = in_sizes[0] / D_IN;
  const int E = in_sizes[1];
  if (ws_size < WS_NEEDED) return;

  char*   ws   = (char*)d_ws;
  int*    cur1 = (int*)(ws + CUR1_OFF);
  int*    cur2 = (int*)(ws + CUR2_OFF);
  int*    rp1  = (int*)(ws + RP1_OFF);
  int*    rp2  = (int*)(ws + RP2_OFF);
  int*    bs1  = (int*)(ws + BS1_OFF);
  int*    bs2  = (int*)(ws + BS2_OFF);
  int*    csr1 = (int*)(ws + CSR1_OFF);
  int*    csr2 = (int*)(ws + CSR2_OFF);
  bf16_t* xcat = (bf16_t*)(ws + XCAT_OFF);
  float*  p    = (float*)(ws + P_OFF);
  bf16_t* w1f  = (bf16_t*)(ws + W1F_OFF);
  bf16_t* w2f  = (bf16_t*)(ws + W2F_OFF);

  const int nbN = (N + 255) / 256;   // 391 <= 512
  const int gE  = (E + 255) / 256;

  hipMemsetAsync(ws + CUR1_OFF, 0, ZERO_BYTES, stream);

  k_convx<<<(N * 16 + 255) / 256, 256, 0, stream>>>(x, xcat, N);
  k_conv_w<<<32, 256, 0, stream>>>(ws1, wn1, ws2, wn2, w1f, w2f);
  k_count<<<gE, 256, 0, stream>>>(dst1, dst2, cur1, cur2, E);

  {
    dim3 g(nbN, 2);
    k_scan_block<<<g, 256, 0, stream>>>(cur1, cur2, rp1, rp2, bs1, bs2, N);
  }
  k_scan_sums<<<2, 512, 0, stream>>>(bs1, bs2, nbN);
  {
    dim3 g((N + 256) / 256 + 1, 2);
    k_add_cur<<<g, 256, 0, stream>>>(rp1, rp2, bs1, bs2, cur1, cur2, N, E);
  }
  k_fill<<<gE, 256, 0, stream>>>(src1, dst1, src2, dst2, cur1, cur2, csr1, csr2, E);

  k_agg1<<<(N * 16 + 255) / 256, 256, 0, stream>>>(xcat, rp1, csr1, N);
  k_fused<<<(N + 63) / 64, 256, 0, stream>>>(xcat, w1f, b1, w2f, b2, out, p, N);
  k_agg2fin<<<(N * 10 + 255) / 256, 256, 0, stream>>>(p, rp2, csr2, out, N);
}

// Round 4
// 179.850 us; speedup vs baseline: 8.9442x; 1.5722x over previous
//
#include <hip/hip_runtime.h>
#include <hip/hip_bf16.h>
#include <cstdint>
#include <cstddef>

// ---------------------------------------------------------------------------
// GraphSAGE 2-layer forward (mean aggregator), MI355X / gfx950.
//
//   h  = relu(x @ Ws1.T + mean_nbr1(x) @ Wn1.T + b1)
//   out = h @ Ws2.T + mean_nbr2(h) @ Wn2.T + b2
//
// Structure (round 4):
//   xcat[N][256] = [ bf16(x) | bf16(mean1(x)) ]
//   fused GEMM: per 64-row tile, phase A: h=relu(xcat@w1f.T+b1) -> LDS;
//               phase B: [s|p] = h_lds @ w2f.T; s+b2 -> out, p -> ws
//   k_agg2fin: out += mean2(p)
//   CSR build is a two-level bucket sort with ZERO global atomics:
//     k_hist:  per-chunk LDS histogram over 391 buckets (dst>>8)
//     scan:    global excl scan of histG[bucket][chunk] (50048 ints/layer)
//     k_scat:  re-read chunk, LDS cursors -> bucketed u32 (src | ld<<24)
//     k_bcsr:  per-bucket LDS counting sort -> coalesced CSR + rowptr
//              (csr aliases the bucket buffer: reads precede writes)
//
// Round-1 lesson: fp32-atomic scatter = atomic-bound (1009us).
// Round-2 lesson: f32 A-frags from global + strided B = latency-bound GEMM.
// Round-3 lesson: global-atomic CSR fill = 84MB HBM RMW for 4.8MB payload
//   (atomics bypass L2); replace with LDS-binned counting sort.
// ---------------------------------------------------------------------------

#define D_IN 128
#define D_H  256
#define D_C  40

#define NBLK     128      // chunks per layer for hist/scatter
#define NBKT_MAX 392      // max coarse buckets (ceil(100000/256)=391)
#define BKT_CAP  2560     // max edges per bucket staged in LDS (mean 1536)

typedef __bf16 bf16_t;
typedef __attribute__((ext_vector_type(8))) __bf16 bf16x8;
typedef __attribute__((ext_vector_type(4))) float  f32x4;

// ---------------- ws layout (bytes), 256B-aligned ----------------
static constexpr size_t NMAX = 100000;
static constexpr size_t EMAX = 600000;
static constexpr size_t NSC_MAX = (size_t)NBKT_MAX * NBLK;   // scan length
static constexpr size_t alignup(size_t v) { return (v + 255) & ~size_t(255); }

static constexpr size_t HG1_OFF  = 0;                                   // int[NSC]
static constexpr size_t HG2_OFF  = alignup(HG1_OFF + NSC_MAX * 4);      // int[NSC]
static constexpr size_t BS1_OFF  = alignup(HG2_OFF + NSC_MAX * 4);      // int[512]
static constexpr size_t BS2_OFF  = alignup(BS1_OFF + 512 * 4);
static constexpr size_t RP1_OFF  = alignup(BS2_OFF + 512 * 4);          // int[N+1]
static constexpr size_t RP2_OFF  = alignup(RP1_OFF + (NMAX + 1) * 4);
static constexpr size_t BKT1_OFF = alignup(RP2_OFF + (NMAX + 1) * 4);   // u32[E] (later csr1)
static constexpr size_t BKT2_OFF = alignup(BKT1_OFF + EMAX * 4);        // u32[E] (later csr2)
static constexpr size_t XCAT_OFF = alignup(BKT2_OFF + EMAX * 4);        // bf16[N][256]
static constexpr size_t P_OFF    = alignup(XCAT_OFF + NMAX * 256 * 2);  // f32[N][40]
static constexpr size_t W1F_OFF  = alignup(P_OFF + NMAX * 40 * 4);      // bf16 32*256*8
static constexpr size_t W2F_OFF  = alignup(W1F_OFF + 32 * 256 * 8 * 2); // bf16 32*80*8
static constexpr size_t WS_NEEDED = W2F_OFF + 32 * 80 * 8 * 2;

// ---------------- x -> bf16 into xcat[:,0:128] ----------------
__global__ void k_convx(const float* __restrict__ x, bf16_t* __restrict__ xcat, int N) {
  int t = blockIdx.x * 256 + threadIdx.x;
  if (t >= N * 16) return;
  int row = t >> 4, j = t & 15;
  const float* sp = x + (size_t)row * 128 + j * 8;
  float4 v0 = ((const float4*)sp)[0];
  float4 v1 = ((const float4*)sp)[1];
  bf16x8 o;
  o[0] = (bf16_t)v0.x; o[1] = (bf16_t)v0.y; o[2] = (bf16_t)v0.z; o[3] = (bf16_t)v0.w;
  o[4] = (bf16_t)v1.x; o[5] = (bf16_t)v1.y; o[6] = (bf16_t)v1.z; o[7] = (bf16_t)v1.w;
  *(bf16x8*)(xcat + (size_t)row * 256 + j * 8) = o;
}

// ---------------- weights -> bf16, fragment-major ----------------
__global__ void k_conv_w(const float* __restrict__ ws1, const float* __restrict__ wn1,
                         const float* __restrict__ ws2, const float* __restrict__ wn2,
                         bf16_t* __restrict__ w1f, bf16_t* __restrict__ w2f) {
  int t = blockIdx.x * 256 + threadIdx.x;
  if (t < 32 * 256) {
    int ks4g = t >> 8, col = t & 255;
    int k0 = (ks4g >> 2) * 32 + (ks4g & 3) * 8;
    bf16x8 o;
#pragma unroll
    for (int i = 0; i < 8; ++i) {
      int k = k0 + i;   // K-concat: k<128 -> Ws1, else Wn1
      float v = (k < 128) ? ws1[col * 128 + k] : wn1[col * 128 + (k - 128)];
      o[i] = (bf16_t)v;
    }
    *(bf16x8*)(w1f + (size_t)t * 8) = o;
  }
  if (t < 32 * 80) {
    int ks4g = t / 80, col = t - ks4g * 80;
    int k0 = (ks4g >> 2) * 32 + (ks4g & 3) * 8;
    bf16x8 o;
#pragma unroll
    for (int i = 0; i < 8; ++i) {
      int k = k0 + i;   // col-concat: col<40 -> Ws2, else Wn2
      float v = (col < 40) ? ws2[col * 256 + k] : wn2[(col - 40) * 256 + k];
      o[i] = (bf16_t)v;
    }
    *(bf16x8*)(w2f + (size_t)t * 8) = o;
  }
}

// ---------------- pass 1: per-chunk bucket histogram (LDS atomics only) ----------------
__global__ void k_hist(const int* __restrict__ dst1, const int* __restrict__ dst2,
                       int* __restrict__ hg1, int* __restrict__ hg2,
                       int E, int chunk, int nbkt) {
  const int* dst = blockIdx.y ? dst2 : dst1;
  int*       hg  = blockIdx.y ? hg2 : hg1;
  __shared__ int h[NBKT_MAX];
  for (int i = threadIdx.x; i < nbkt; i += 256) h[i] = 0;
  __syncthreads();
  int beg = blockIdx.x * chunk, end = min(E, beg + chunk);
  for (int e = beg + threadIdx.x; e < end; e += 256)
    atomicAdd(&h[dst[e] >> 8], 1);
  __syncthreads();
  for (int b = threadIdx.x; b < nbkt; b += 256)
    hg[b * NBLK + blockIdx.x] = h[b];   // bucket-major, chunk-minor
}

// ---------------- hierarchical exclusive scan (in-place) ----------------
__global__ void k_scan_block(int* __restrict__ a1, int* __restrict__ a2,
                             int* __restrict__ b1s, int* __restrict__ b2s, int n) {
  int* a    = blockIdx.y ? a2 : a1;
  int* bsum = blockIdx.y ? b2s : b1s;
  __shared__ int lds[256];
  int t = threadIdx.x, i = blockIdx.x * 256 + t;
  int v = (i < n) ? a[i] : 0;
  lds[t] = v;
  __syncthreads();
  for (int off = 1; off < 256; off <<= 1) {
    int add = (t >= off) ? lds[t - off] : 0;
    __syncthreads();
    lds[t] += add;
    __syncthreads();
  }
  if (i < n) a[i] = lds[t] - v;               // exclusive
  if (t == 255) bsum[blockIdx.x] = lds[255];  // block total
}

__global__ void k_scan_sums(int* __restrict__ b1s, int* __restrict__ b2s, int nb) {
  int* bsum = blockIdx.x ? b2s : b1s;
  __shared__ int lds[512];
  int t = threadIdx.x;
  int v = (t < nb) ? bsum[t] : 0;
  lds[t] = v;
  __syncthreads();
  for (int off = 1; off < 512; off <<= 1) {
    int add = (t >= off) ? lds[t - off] : 0;
    __syncthreads();
    lds[t] += add;
    __syncthreads();
  }
  if (t < nb) bsum[t] = lds[t] - v;           // exclusive
}

__global__ void k_scan_add(int* __restrict__ a1, int* __restrict__ a2,
                           const int* __restrict__ b1s, const int* __restrict__ b2s, int n) {
  int* a        = blockIdx.y ? a2 : a1;
  const int* bs = blockIdx.y ? b2s : b1s;
  int i = blockIdx.x * 256 + threadIdx.x;
  if (i < n) a[i] += bs[i >> 8];
}

// ---------------- pass 2: scatter into bucketed array (LDS cursors) ----------------
// bkt value: src | (dst&255)<<24   (src < 2^17 fits low 24 bits)
__global__ void k_scat(const int* __restrict__ src1, const int* __restrict__ dst1,
                       const int* __restrict__ src2, const int* __restrict__ dst2,
                       const int* __restrict__ off1, const int* __restrict__ off2,
                       unsigned* __restrict__ bkt1, unsigned* __restrict__ bkt2,
                       int E, int chunk, int nbkt) {
  const int* src = blockIdx.y ? src2 : src1;
  const int* dst = blockIdx.y ? dst2 : dst1;
  const int* off = blockIdx.y ? off2 : off1;
  unsigned*  bkt = blockIdx.y ? bkt2 : bkt1;
  __shared__ int cur[NBKT_MAX];
  for (int i = threadIdx.x; i < nbkt; i += 256)
    cur[i] = off[i * NBLK + blockIdx.x];
  __syncthreads();
  int beg = blockIdx.x * chunk, end = min(E, beg + chunk);
  for (int e = beg + threadIdx.x; e < end; e += 256) {
    int d = dst[e];
    int slot = atomicAdd(&cur[d >> 8], 1);
    bkt[slot] = (unsigned)src[e] | ((unsigned)(d & 255) << 24);
  }
}

// ---------------- pass 3: per-bucket LDS counting sort -> CSR + rowptr ----------------
// csr may alias bkt: all bkt reads precede csr writes (barrier between).
__global__ __launch_bounds__(256) void k_bcsr(
    const int* __restrict__ off1, const int* __restrict__ off2,
    const unsigned* bkt1, const unsigned* bkt2,
    int* csr1, int* csr2,
    int* __restrict__ rp1, int* __restrict__ rp2, int E, int N, int nbkt) {
  const int* off      = blockIdx.y ? off2 : off1;
  const unsigned* bkt = blockIdx.y ? bkt2 : bkt1;
  int* csr            = blockIdx.y ? csr2 : csr1;
  int* rowptr         = blockIdx.y ? rp2 : rp1;

  const int b = blockIdx.x, t = threadIdx.x;
  const int base = off[b * NBLK];
  const int endp = (b == nbkt - 1) ? E : off[(b + 1) * NBLK];
  const int cnt  = endp - base;

  __shared__ int hist[256];
  __shared__ int sc[256];
  __shared__ int cur[256];
  __shared__ int stage[BKT_CAP];

  hist[t] = 0;
  __syncthreads();
  for (int i = t; i < cnt; i += 256)
    atomicAdd(&hist[bkt[base + i] >> 24], 1);
  __syncthreads();

  // exclusive scan of hist
  int v = hist[t];
  sc[t] = v;
  __syncthreads();
  for (int off_ = 1; off_ < 256; off_ <<= 1) {
    int add = (t >= off_) ? sc[t - off_] : 0;
    __syncthreads();
    sc[t] += add;
    __syncthreads();
  }
  int excl = sc[t] - v;

  int node = b * 256 + t;
  if (node < N) rowptr[node] = base + excl;
  if (b == nbkt - 1 && t == 0) rowptr[N] = E;
  cur[t] = excl;
  __syncthreads();

  for (int i = t; i < cnt; i += 256) {
    unsigned u = bkt[base + i];
    int slot = atomicAdd(&cur[u >> 24], 1);
    if (slot < BKT_CAP) stage[slot] = (int)(u & 0xFFFFFFu);
  }
  __syncthreads();
  for (int i = t; i < cnt; i += 256)
    csr[base + i] = stage[i];
}

// ---------------- layer-1 mean -> xcat[:,128:256] (bf16 gather) ----------------
// 16 lanes/node, bf16x8 per lane (reads the x-half, 256B per neighbor row).
__global__ void k_agg1(bf16_t* __restrict__ xcat, const int* __restrict__ rowptr,
                       const int* __restrict__ csr, int N) {
  int t = blockIdx.x * 256 + threadIdx.x;
  int node = t >> 4, l = t & 15;
  if (node >= N) return;
  int beg = rowptr[node], end = rowptr[node + 1];
  float acc[8] = {0.f, 0.f, 0.f, 0.f, 0.f, 0.f, 0.f, 0.f};
  for (int e = beg; e < end; ++e) {
    int s = csr[e];
    bf16x8 v = *(const bf16x8*)(xcat + (size_t)s * 256 + l * 8);
#pragma unroll
    for (int i = 0; i < 8; ++i) acc[i] += (float)v[i];
  }
  float rd = (end > beg) ? 1.0f / (float)(end - beg) : 0.0f;
  bf16x8 o;
#pragma unroll
  for (int i = 0; i < 8; ++i) o[i] = (bf16_t)(acc[i] * rd);
  *(bf16x8*)(xcat + (size_t)node * 256 + 128 + l * 8) = o;
}

// ---------------- fused layer1 GEMM + layer2 GEMM ----------------
__global__ __launch_bounds__(256) void k_fused(
    const bf16_t* __restrict__ xcat, const bf16_t* __restrict__ w1f,
    const float* __restrict__ b1, const bf16_t* __restrict__ w2f,
    const float* __restrict__ b2v, float* __restrict__ out,
    float* __restrict__ p, int N) {
  __shared__ bf16_t hlds[64 * 264];   // pad 256->264
  const int m0   = blockIdx.x * 64;
  const int wv   = threadIdx.x >> 6;
  const int lane = threadIdx.x & 63;
  const int lr   = lane & 15;
  const int lg   = lane >> 4;
  const int c0   = wv * 64;

  // ---- phase A ----
  f32x4 acc[4][4] = {};
  int rows[4];
#pragma unroll
  for (int m = 0; m < 4; ++m) {
    int r = m0 + m * 16 + lr;
    rows[m] = (r < N) ? r : (N - 1);
  }

#pragma unroll
  for (int ks = 0; ks < 8; ++ks) {
    const int kk = ks * 32 + lg * 8;
    bf16x8 a[4];
#pragma unroll
    for (int m = 0; m < 4; ++m)
      a[m] = *(const bf16x8*)(xcat + (size_t)rows[m] * 256 + kk);
    bf16x8 b[4];
#pragma unroll
    for (int bn = 0; bn < 4; ++bn) {
      int col = c0 + bn * 16 + lr;
      b[bn] = *(const bf16x8*)(w1f + ((size_t)(ks * 4 + lg) * 256 + col) * 8);
    }
#pragma unroll
    for (int m = 0; m < 4; ++m)
#pragma unroll
      for (int bn = 0; bn < 4; ++bn)
        acc[m][bn] = __builtin_amdgcn_mfma_f32_16x16x32_bf16(a[m], b[bn], acc[m][bn], 0, 0, 0);
  }

#pragma unroll
  for (int bn = 0; bn < 4; ++bn) {
    int   col  = c0 + bn * 16 + lr;
    float bias = b1[col];
#pragma unroll
    for (int m = 0; m < 4; ++m) {
#pragma unroll
      for (int i = 0; i < 4; ++i) {
        int row = m * 16 + lg * 4 + i;
        float v = acc[m][bn][i] + bias;
        hlds[row * 264 + col] = (bf16_t)fmaxf(v, 0.0f);
      }
    }
  }
  __syncthreads();

  // ---- phase B ----
  f32x4 acc2[5] = {};
  const int arow = wv * 16 + lr;
#pragma unroll
  for (int ks = 0; ks < 8; ++ks) {
    const int kk = ks * 32 + lg * 8;
    bf16x8 a2 = *(const bf16x8*)(hlds + arow * 264 + kk);
#pragma unroll
    for (int bn = 0; bn < 5; ++bn) {
      int col = bn * 16 + lr;
      bf16x8 bb = *(const bf16x8*)(w2f + ((size_t)(ks * 4 + lg) * 80 + col) * 8);
      acc2[bn] = __builtin_amdgcn_mfma_f32_16x16x32_bf16(a2, bb, acc2[bn], 0, 0, 0);
    }
  }

#pragma unroll
  for (int bn = 0; bn < 5; ++bn) {
    int col = bn * 16 + lr;
#pragma unroll
    for (int i = 0; i < 4; ++i) {
      int r = m0 + wv * 16 + lg * 4 + i;
      if (r < N) {
        float v = acc2[bn][i];
        if (col < 40) out[(size_t)r * 40 + col] = v + b2v[col];
        else          p[(size_t)r * 40 + (col - 40)] = v;
      }
    }
  }
}

// ---------------- layer-2 mean fused epilogue: out += mean2(p) ----------------
__global__ void k_agg2fin(const float* __restrict__ p, const int* __restrict__ rowptr,
                          const int* __restrict__ csr, float* __restrict__ out, int N) {
  int t = blockIdx.x * 256 + threadIdx.x;
  int node = t / 10, l = t - node * 10;
  if (node >= N) return;
  int beg = rowptr[node], end = rowptr[node + 1];
  float4 acc = {0.f, 0.f, 0.f, 0.f};
  for (int e = beg; e < end; ++e) {
    int s = csr[e];
    float4 v = *(const float4*)(p + (size_t)s * 40 + l * 4);
    acc.x += v.x; acc.y += v.y; acc.z += v.z; acc.w += v.w;
  }
  float rd = (end > beg) ? 1.0f / (float)(end - beg) : 0.0f;
  float* o = out + (size_t)node * 40 + l * 4;
  float4 cur = *(const float4*)o;
  cur.x += acc.x * rd;
  cur.y += acc.y * rd;
  cur.z += acc.z * rd;
  cur.w += acc.w * rd;
  *(float4*)o = cur;
}

extern "C" void kernel_launch(void* const* d_in, const int* in_sizes, int n_in,
                              void* d_out, int out_size, void* d_ws, size_t ws_size,
                              hipStream_t stream) {
  const float* x    = (const float*)d_in[0];
  const int*   src1 = (const int*)d_in[1];
  const int*   dst1 = (const int*)d_in[2];
  const int*   src2 = (const int*)d_in[3];
  const int*   dst2 = (const int*)d_in[4];
  const float* ws1  = (const float*)d_in[5];
  const float* wn1  = (const float*)d_in[6];
  const float* b1   = (const float*)d_in[7];
  const float* ws2  = (const float*)d_in[8];
  const float* wn2  = (const float*)d_in[9];
  const float* b2   = (const float*)d_in[10];
  float*       out  = (float*)d_out;

  const int N = in_sizes[0] / D_IN;
  const int E = in_sizes[1];
  if (ws_size < WS_NEEDED) return;

  char*     ws   = (char*)d_ws;
  int*      hg1  = (int*)(ws + HG1_OFF);
  int*      hg2  = (int*)(ws + HG2_OFF);
  int*      bs1  = (int*)(ws + BS1_OFF);
  int*      bs2  = (int*)(ws + BS2_OFF);
  int*      rp1  = (int*)(ws + RP1_OFF);
  int*      rp2  = (int*)(ws + RP2_OFF);
  unsigned* bkt1 = (unsigned*)(ws + BKT1_OFF);
  unsigned* bkt2 = (unsigned*)(ws + BKT2_OFF);
  int*      csr1 = (int*)(ws + BKT1_OFF);     // aliases bkt1 (safe: see k_bcsr)
  int*      csr2 = (int*)(ws + BKT2_OFF);     // aliases bkt2
  bf16_t*   xcat = (bf16_t*)(ws + XCAT_OFF);
  float*    p    = (float*)(ws + P_OFF);
  bf16_t*   w1f  = (bf16_t*)(ws + W1F_OFF);
  bf16_t*   w2f  = (bf16_t*)(ws + W2F_OFF);

  const int nbkt  = (N + 255) >> 8;            // 391
  const int chunk = (E + NBLK - 1) / NBLK;     // 4688
  const int nsc   = nbkt * NBLK;               // 50048
  const int nscb  = (nsc + 255) / 256;         // 196 (<=512)

  k_convx<<<(N * 16 + 255) / 256, 256, 0, stream>>>(x, xcat, N);
  k_conv_w<<<32, 256, 0, stream>>>(ws1, wn1, ws2, wn2, w1f, w2f);

  k_hist<<<dim3(NBLK, 2), 256, 0, stream>>>(dst1, dst2, hg1, hg2, E, chunk, nbkt);
  k_scan_block<<<dim3(nscb, 2), 256, 0, stream>>>(hg1, hg2, bs1, bs2, nsc);
  k_scan_sums<<<2, 512, 0, stream>>>(bs1, bs2, nscb);
  k_scan_add<<<dim3(nscb, 2), 256, 0, stream>>>(hg1, hg2, bs1, bs2, nsc);
  k_scat<<<dim3(NBLK, 2), 256, 0, stream>>>(src1, dst1, src2, dst2, hg1, hg2,
                                            bkt1, bkt2, E, chunk, nbkt);
  k_bcsr<<<dim3(nbkt, 2), 256, 0, stream>>>(hg1, hg2, bkt1, bkt2, csr1, csr2,
                                            rp1, rp2, E, N, nbkt);

  k_agg1<<<(N * 16 + 255) / 256, 256, 0, stream>>>(xcat, rp1, csr1, N);
  k_fused<<<(N + 63) / 64, 256, 0, stream>>>(xcat, w1f, b1, w2f, b2, out, p, N);
  k_agg2fin<<<(N * 10 + 255) / 256, 256, 0, stream>>>(p, rp2, csr2, out, N);
}

// Round 5
// 151.949 us; speedup vs baseline: 10.5866x; 1.1836x over previous
//
#include <hip/hip_runtime.h>
#include <hip/hip_bf16.h>
#include <cstdint>
#include <cstddef>

// ---------------------------------------------------------------------------
// GraphSAGE 2-layer forward (mean aggregator), MI355X / gfx950.
//
//   h  = relu(x @ Ws1.T + mean_nbr1(x) @ Wn1.T + b1)
//   out = h @ Ws2.T + mean_nbr2(h) @ Wn2.T + b2
//
// Structure (round 5):
//   k_prep (merged): xcat[:,0:128]=bf16(x); w1f/w2f frag-major bf16;
//                    per-chunk LDS bucket histograms (dst>>8)
//   scan/scat/bcsr:  atomic-free two-level counting sort -> CSR
//   k_agg1:          xcat[:,128:256] = bf16(mean1(x))      (CSR gather)
//   k_fused:         per 64-row tile:
//     stage: global_load_lds A-tile (64x256 bf16 = 32KB) with pre-swizzled
//            source (byte c ^= (row&7)<<4)  -> conflict-free ds_read_b128
//     phase A: h = relu(A @ w1f.T + b1) -> same LDS (barrier-separated,
//              same XOR swizzle; replaces the old +8 padding, LDS = 32KB)
//     phase B: [s|p] = h_lds @ w2f.T; s+b2 -> out, p -> ws
//   k_agg2fin:       out += mean2(p)
//
// Round-1: fp32-atomic scatter = atomic-bound (1009us) -> CSR gather.
// Round-2: f32 A-frags from global + strided B = latency-bound GEMM (5% mfma).
// Round-3: global-atomic CSR fill = 84MB HBM RMW for 4.8MB -> LDS sort.
// Round-4: k_fused still latency-bound (9% mfma, 11% BW): redundant per-wave
//   global A-loads -> LDS-staged A via global_load_lds + swizzle.
// ---------------------------------------------------------------------------

#define D_IN 128
#define D_H  256
#define D_C  40

#define NBLK     128      // chunks per layer for hist/scatter
#define NBKT_MAX 392      // max coarse buckets (ceil(100000/256)=391)
#define BKT_CAP  2560     // max edges per bucket staged in LDS (mean 1536)

typedef __bf16 bf16_t;
typedef __attribute__((ext_vector_type(8))) __bf16 bf16x8;
typedef __attribute__((ext_vector_type(4))) float  f32x4;

// ---------------- ws layout (bytes), 256B-aligned ----------------
static constexpr size_t NMAX = 100000;
static constexpr size_t EMAX = 600000;
static constexpr size_t NSC_MAX = (size_t)NBKT_MAX * NBLK;
static constexpr size_t alignup(size_t v) { return (v + 255) & ~size_t(255); }

static constexpr size_t HG1_OFF  = 0;                                   // int[NSC]
static constexpr size_t HG2_OFF  = alignup(HG1_OFF + NSC_MAX * 4);      // int[NSC]
static constexpr size_t BS1_OFF  = alignup(HG2_OFF + NSC_MAX * 4);      // int[512]
static constexpr size_t BS2_OFF  = alignup(BS1_OFF + 512 * 4);
static constexpr size_t RP1_OFF  = alignup(BS2_OFF + 512 * 4);          // int[N+1]
static constexpr size_t RP2_OFF  = alignup(RP1_OFF + (NMAX + 1) * 4);
static constexpr size_t BKT1_OFF = alignup(RP2_OFF + (NMAX + 1) * 4);   // u32[E] (later csr1)
static constexpr size_t BKT2_OFF = alignup(BKT1_OFF + EMAX * 4);        // u32[E] (later csr2)
static constexpr size_t XCAT_OFF = alignup(BKT2_OFF + EMAX * 4);        // bf16[N+64][256] (+tile slack)
static constexpr size_t P_OFF    = alignup(XCAT_OFF + (NMAX + 64) * 256 * 2);
static constexpr size_t W1F_OFF  = alignup(P_OFF + NMAX * 40 * 4);      // bf16 32*256*8
static constexpr size_t W2F_OFF  = alignup(W1F_OFF + 32 * 256 * 8 * 2); // bf16 32*80*8
static constexpr size_t WS_NEEDED = W2F_OFF + 32 * 80 * 8 * 2;

// ---------------- merged prep: convx + conv_w + hist ----------------
__global__ __launch_bounds__(256) void k_prep(
    const float* __restrict__ x, bf16_t* __restrict__ xcat,
    const float* __restrict__ ws1, const float* __restrict__ wn1,
    const float* __restrict__ ws2, const float* __restrict__ wn2,
    bf16_t* __restrict__ w1f, bf16_t* __restrict__ w2f,
    const int* __restrict__ dst1, const int* __restrict__ dst2,
    int* __restrict__ hg1, int* __restrict__ hg2,
    int N, int E, int chunk, int nbkt, int nconvx) {
  __shared__ int h[NBKT_MAX];
  int bid = blockIdx.x;

  if (bid < nconvx) {                       // ---- x -> bf16 into xcat[:,0:128]
    int t = bid * 256 + threadIdx.x;
    if (t < N * 16) {
      int row = t >> 4, j = t & 15;
      const float* sp = x + (size_t)row * 128 + j * 8;
      float4 v0 = ((const float4*)sp)[0];
      float4 v1 = ((const float4*)sp)[1];
      bf16x8 o;
      o[0] = (bf16_t)v0.x; o[1] = (bf16_t)v0.y; o[2] = (bf16_t)v0.z; o[3] = (bf16_t)v0.w;
      o[4] = (bf16_t)v1.x; o[5] = (bf16_t)v1.y; o[6] = (bf16_t)v1.z; o[7] = (bf16_t)v1.w;
      *(bf16x8*)(xcat + (size_t)row * 256 + j * 8) = o;
    }
    return;
  }
  bid -= nconvx;

  if (bid < 32) {                           // ---- weights -> bf16 frag-major
    int t = bid * 256 + threadIdx.x;
    {
      int ks4g = t >> 8, col = t & 255;
      int k0 = (ks4g >> 2) * 32 + (ks4g & 3) * 8;
      bf16x8 o;
#pragma unroll
      for (int i = 0; i < 8; ++i) {
        int k = k0 + i;   // K-concat: k<128 -> Ws1, else Wn1
        float v = (k < 128) ? ws1[col * 128 + k] : wn1[col * 128 + (k - 128)];
        o[i] = (bf16_t)v;
      }
      *(bf16x8*)(w1f + (size_t)t * 8) = o;
    }
    if (t < 32 * 80) {
      int ks4g = t / 80, col = t - ks4g * 80;
      int k0 = (ks4g >> 2) * 32 + (ks4g & 3) * 8;
      bf16x8 o;
#pragma unroll
      for (int i = 0; i < 8; ++i) {
        int k = k0 + i;   // col-concat: col<40 -> Ws2, else Wn2
        float v = (col < 40) ? ws2[col * 256 + k] : wn2[(col - 40) * 256 + k];
        o[i] = (bf16_t)v;
      }
      *(bf16x8*)(w2f + (size_t)t * 8) = o;
    }
    return;
  }
  bid -= 32;                                 // ---- histogram: bid in [0, 256)
  {
    const int* dst = (bid >> 7) ? dst2 : dst1;
    int*       hg  = (bid >> 7) ? hg2 : hg1;
    int        cb  = bid & 127;
    for (int i = threadIdx.x; i < nbkt; i += 256) h[i] = 0;
    __syncthreads();
    int beg = cb * chunk, end = min(E, beg + chunk);
    for (int e = beg + threadIdx.x; e < end; e += 256)
      atomicAdd(&h[dst[e] >> 8], 1);
    __syncthreads();
    for (int b = threadIdx.x; b < nbkt; b += 256)
      hg[b * NBLK + cb] = h[b];   // bucket-major, chunk-minor
  }
}

// ---------------- hierarchical exclusive scan (in-place) ----------------
__global__ void k_scan_block(int* __restrict__ a1, int* __restrict__ a2,
                             int* __restrict__ b1s, int* __restrict__ b2s, int n) {
  int* a    = blockIdx.y ? a2 : a1;
  int* bsum = blockIdx.y ? b2s : b1s;
  __shared__ int lds[256];
  int t = threadIdx.x, i = blockIdx.x * 256 + t;
  int v = (i < n) ? a[i] : 0;
  lds[t] = v;
  __syncthreads();
  for (int off = 1; off < 256; off <<= 1) {
    int add = (t >= off) ? lds[t - off] : 0;
    __syncthreads();
    lds[t] += add;
    __syncthreads();
  }
  if (i < n) a[i] = lds[t] - v;
  if (t == 255) bsum[blockIdx.x] = lds[255];
}

__global__ void k_scan_sums(int* __restrict__ b1s, int* __restrict__ b2s, int nb) {
  int* bsum = blockIdx.x ? b2s : b1s;
  __shared__ int lds[512];
  int t = threadIdx.x;
  int v = (t < nb) ? bsum[t] : 0;
  lds[t] = v;
  __syncthreads();
  for (int off = 1; off < 512; off <<= 1) {
    int add = (t >= off) ? lds[t - off] : 0;
    __syncthreads();
    lds[t] += add;
    __syncthreads();
  }
  if (t < nb) bsum[t] = lds[t] - v;
}

__global__ void k_scan_add(int* __restrict__ a1, int* __restrict__ a2,
                           const int* __restrict__ b1s, const int* __restrict__ b2s, int n) {
  int* a        = blockIdx.y ? a2 : a1;
  const int* bs = blockIdx.y ? b2s : b1s;
  int i = blockIdx.x * 256 + threadIdx.x;
  if (i < n) a[i] += bs[i >> 8];
}

// ---------------- scatter into bucketed array (LDS cursors) ----------------
__global__ void k_scat(const int* __restrict__ src1, const int* __restrict__ dst1,
                       const int* __restrict__ src2, const int* __restrict__ dst2,
                       const int* __restrict__ off1, const int* __restrict__ off2,
                       unsigned* __restrict__ bkt1, unsigned* __restrict__ bkt2,
                       int E, int chunk, int nbkt) {
  const int* src = blockIdx.y ? src2 : src1;
  const int* dst = blockIdx.y ? dst2 : dst1;
  const int* off = blockIdx.y ? off2 : off1;
  unsigned*  bkt = blockIdx.y ? bkt2 : bkt1;
  __shared__ int cur[NBKT_MAX];
  for (int i = threadIdx.x; i < nbkt; i += 256)
    cur[i] = off[i * NBLK + blockIdx.x];
  __syncthreads();
  int beg = blockIdx.x * chunk, end = min(E, beg + chunk);
  for (int e = beg + threadIdx.x; e < end; e += 256) {
    int d = dst[e];
    int slot = atomicAdd(&cur[d >> 8], 1);
    bkt[slot] = (unsigned)src[e] | ((unsigned)(d & 255) << 24);
  }
}

// ---------------- per-bucket LDS counting sort -> CSR + rowptr ----------------
__global__ __launch_bounds__(256) void k_bcsr(
    const int* __restrict__ off1, const int* __restrict__ off2,
    const unsigned* bkt1, const unsigned* bkt2,
    int* csr1, int* csr2,
    int* __restrict__ rp1, int* __restrict__ rp2, int E, int N, int nbkt) {
  const int* off      = blockIdx.y ? off2 : off1;
  const unsigned* bkt = blockIdx.y ? bkt2 : bkt1;
  int* csr            = blockIdx.y ? csr2 : csr1;
  int* rowptr         = blockIdx.y ? rp2 : rp1;

  const int b = blockIdx.x, t = threadIdx.x;
  const int base = off[b * NBLK];
  const int endp = (b == nbkt - 1) ? E : off[(b + 1) * NBLK];
  const int cnt  = endp - base;

  __shared__ int hist[256];
  __shared__ int sc[256];
  __shared__ int cur[256];
  __shared__ int stage[BKT_CAP];

  hist[t] = 0;
  __syncthreads();
  for (int i = t; i < cnt; i += 256)
    atomicAdd(&hist[bkt[base + i] >> 24], 1);
  __syncthreads();

  int v = hist[t];
  sc[t] = v;
  __syncthreads();
  for (int off_ = 1; off_ < 256; off_ <<= 1) {
    int add = (t >= off_) ? sc[t - off_] : 0;
    __syncthreads();
    sc[t] += add;
    __syncthreads();
  }
  int excl = sc[t] - v;

  int node = b * 256 + t;
  if (node < N) rowptr[node] = base + excl;
  if (b == nbkt - 1 && t == 0) rowptr[N] = E;
  cur[t] = excl;
  __syncthreads();

  for (int i = t; i < cnt; i += 256) {
    unsigned u = bkt[base + i];
    int slot = atomicAdd(&cur[u >> 24], 1);
    if (slot < BKT_CAP) stage[slot] = (int)(u & 0xFFFFFFu);
  }
  __syncthreads();
  for (int i = t; i < cnt; i += 256)
    csr[base + i] = stage[i];
}

// ---------------- layer-1 mean -> xcat[:,128:256] (bf16 gather) ----------------
__global__ void k_agg1(bf16_t* __restrict__ xcat, const int* __restrict__ rowptr,
                       const int* __restrict__ csr, int N) {
  int t = blockIdx.x * 256 + threadIdx.x;
  int node = t >> 4, l = t & 15;
  if (node >= N) return;
  int beg = rowptr[node], end = rowptr[node + 1];
  float acc[8] = {0.f, 0.f, 0.f, 0.f, 0.f, 0.f, 0.f, 0.f};
  for (int e = beg; e < end; ++e) {
    int s = csr[e];
    bf16x8 v = *(const bf16x8*)(xcat + (size_t)s * 256 + l * 8);
#pragma unroll
    for (int i = 0; i < 8; ++i) acc[i] += (float)v[i];
  }
  float rd = (end > beg) ? 1.0f / (float)(end - beg) : 0.0f;
  bf16x8 o;
#pragma unroll
  for (int i = 0; i < 8; ++i) o[i] = (bf16_t)(acc[i] * rd);
  *(bf16x8*)(xcat + (size_t)node * 256 + 128 + l * 8) = o;
}

// ---------------- fused layer1 GEMM + layer2 GEMM (LDS-staged A) ----------------
// LDS: ONE 32KB buffer. First holds the swizzled A-tile (64x256 bf16), then
// (after a barrier) the h-tile in the same swizzled layout.
// Swizzle: byte_off_in_row c -> c ^ ((row&7)<<4). Involution; applied on the
// GLOBAL source during global_load_lds staging (m173 pattern) and on every
// ds access. Wave A/h reads: 16 lanes same lg spread over 8 bank-groups
// -> 2-way conflict (free, m136).
__global__ __launch_bounds__(256, 4) void k_fused(
    const bf16_t* __restrict__ xcat, const bf16_t* __restrict__ w1f,
    const float* __restrict__ b1, const bf16_t* __restrict__ w2f,
    const float* __restrict__ b2v, float* __restrict__ out,
    float* __restrict__ p, int N) {
  __shared__ __align__(16) char lds[32768];
  const int m0   = blockIdx.x * 64;
  const int wv   = threadIdx.x >> 6;
  const int lane = threadIdx.x & 63;
  const int lr   = lane & 15;
  const int lg   = lane >> 4;
  const int c0   = wv * 64;

  // ---- stage A-tile: 8 x global_load_lds dwordx4, pre-swizzled source ----
  {
    const char* tbase = (const char*)(xcat + (size_t)m0 * 256);
#pragma unroll
    for (int i = 0; i < 8; ++i) {
      int L   = i * 4096 + (int)threadIdx.x * 16;      // linear LDS byte offset
      int row = L >> 9;
      int c   = L & 511;
      int so  = (row << 9) | (c ^ ((row & 7) << 4));   // inverse-swizzled source
      __builtin_amdgcn_global_load_lds(
          (const __attribute__((address_space(1))) void*)(tbase + so),
          (__attribute__((address_space(3))) void*)(lds + L), 16, 0, 0);
    }
  }
  __syncthreads();

  // ---- phase A: h = relu(A @ w1f.T + b1) ----
  f32x4 acc[4][4] = {};
#pragma unroll
  for (int ks = 0; ks < 8; ++ks) {
    bf16x8 a[4];
#pragma unroll
    for (int m = 0; m < 4; ++m) {
      int lrow = m * 16 + lr;
      int c    = ks * 64 + lg * 16;
      a[m] = *(const bf16x8*)(lds + lrow * 512 + (c ^ ((lrow & 7) << 4)));
    }
    bf16x8 b[4];
#pragma unroll
    for (int bn = 0; bn < 4; ++bn) {
      int col = c0 + bn * 16 + lr;
      b[bn] = *(const bf16x8*)(w1f + ((size_t)(ks * 4 + lg) * 256 + col) * 8);
    }
#pragma unroll
    for (int m = 0; m < 4; ++m)
#pragma unroll
      for (int bn = 0; bn < 4; ++bn)
        acc[m][bn] = __builtin_amdgcn_mfma_f32_16x16x32_bf16(a[m], b[bn], acc[m][bn], 0, 0, 0);
  }
  __syncthreads();   // all waves done reading A before h overwrites

  // ---- epilogue A -> same LDS (swizzled), C/D: col=lane&15, row=(lane>>4)*4+i
#pragma unroll
  for (int bn = 0; bn < 4; ++bn) {
    int   col  = c0 + bn * 16 + lr;
    float bias = b1[col];
#pragma unroll
    for (int m = 0; m < 4; ++m) {
#pragma unroll
      for (int i = 0; i < 4; ++i) {
        int row = m * 16 + lg * 4 + i;
        float v = acc[m][bn][i] + bias;
        *(bf16_t*)(lds + row * 512 + ((col * 2) ^ ((row & 7) << 4))) =
            (bf16_t)fmaxf(v, 0.0f);
      }
    }
  }
  __syncthreads();

  // ---- phase B: [s|p] = h @ w2f.T ----
  f32x4 acc2[5] = {};
  const int arow = wv * 16 + lr;
#pragma unroll
  for (int ks = 0; ks < 8; ++ks) {
    int c = ks * 64 + lg * 16;
    bf16x8 a2 = *(const bf16x8*)(lds + arow * 512 + (c ^ ((arow & 7) << 4)));
#pragma unroll
    for (int bn = 0; bn < 5; ++bn) {
      int col = bn * 16 + lr;
      bf16x8 bb = *(const bf16x8*)(w2f + ((size_t)(ks * 4 + lg) * 80 + col) * 8);
      acc2[bn] = __builtin_amdgcn_mfma_f32_16x16x32_bf16(a2, bb, acc2[bn], 0, 0, 0);
    }
  }

#pragma unroll
  for (int bn = 0; bn < 5; ++bn) {
    int col = bn * 16 + lr;
#pragma unroll
    for (int i = 0; i < 4; ++i) {
      int r = m0 + wv * 16 + lg * 4 + i;
      if (r < N) {
        float v = acc2[bn][i];
        if (col < 40) out[(size_t)r * 40 + col] = v + b2v[col];
        else          p[(size_t)r * 40 + (col - 40)] = v;
      }
    }
  }
}

// ---------------- layer-2 mean fused epilogue: out += mean2(p) ----------------
__global__ void k_agg2fin(const float* __restrict__ p, const int* __restrict__ rowptr,
                          const int* __restrict__ csr, float* __restrict__ out, int N) {
  int t = blockIdx.x * 256 + threadIdx.x;
  int node = t / 10, l = t - node * 10;
  if (node >= N) return;
  int beg = rowptr[node], end = rowptr[node + 1];
  float4 acc = {0.f, 0.f, 0.f, 0.f};
  for (int e = beg; e < end; ++e) {
    int s = csr[e];
    float4 v = *(const float4*)(p + (size_t)s * 40 + l * 4);
    acc.x += v.x; acc.y += v.y; acc.z += v.z; acc.w += v.w;
  }
  float rd = (end > beg) ? 1.0f / (float)(end - beg) : 0.0f;
  float* o = out + (size_t)node * 40 + l * 4;
  float4 cur = *(const float4*)o;
  cur.x += acc.x * rd;
  cur.y += acc.y * rd;
  cur.z += acc.z * rd;
  cur.w += acc.w * rd;
  *(float4*)o = cur;
}

extern "C" void kernel_launch(void* const* d_in, const int* in_sizes, int n_in,
                              void* d_out, int out_size, void* d_ws, size_t ws_size,
                              hipStream_t stream) {
  const float* x    = (const float*)d_in[0];
  const int*   src1 = (const int*)d_in[1];
  const int*   dst1 = (const int*)d_in[2];
  const int*   src2 = (const int*)d_in[3];
  const int*   dst2 = (const int*)d_in[4];
  const float* ws1  = (const float*)d_in[5];
  const float* wn1  = (const float*)d_in[6];
  const float* b1   = (const float*)d_in[7];
  const float* ws2  = (const float*)d_in[8];
  const float* wn2  = (const float*)d_in[9];
  const float* b2   = (const float*)d_in[10];
  float*       out  = (float*)d_out;

  const int N = in_sizes[0] / D_IN;
  const int E = in_sizes[1];
  if (ws_size < WS_NEEDED) return;

  char*     ws   = (char*)d_ws;
  int*      hg1  = (int*)(ws + HG1_OFF);
  int*      hg2  = (int*)(ws + HG2_OFF);
  int*      bs1  = (int*)(ws + BS1_OFF);
  int*      bs2  = (int*)(ws + BS2_OFF);
  int*      rp1  = (int*)(ws + RP1_OFF);
  int*      rp2  = (int*)(ws + RP2_OFF);
  unsigned* bkt1 = (unsigned*)(ws + BKT1_OFF);
  unsigned* bkt2 = (unsigned*)(ws + BKT2_OFF);
  int*      csr1 = (int*)(ws + BKT1_OFF);     // aliases bkt1 (safe: see k_bcsr)
  int*      csr2 = (int*)(ws + BKT2_OFF);     // aliases bkt2
  bf16_t*   xcat = (bf16_t*)(ws + XCAT_OFF);
  float*    p    = (float*)(ws + P_OFF);
  bf16_t*   w1f  = (bf16_t*)(ws + W1F_OFF);
  bf16_t*   w2f  = (bf16_t*)(ws + W2F_OFF);

  const int nbkt  = (N + 255) >> 8;            // 391
  const int chunk = (E + NBLK - 1) / NBLK;     // 4688
  const int nsc   = nbkt * NBLK;               // 50048
  const int nscb  = (nsc + 255) / 256;         // 196 (<=512)
  const int nconvx = (N * 16 + 255) / 256;     // 6250

  k_prep<<<nconvx + 32 + 2 * NBLK, 256, 0, stream>>>(
      x, xcat, ws1, wn1, ws2, wn2, w1f, w2f, dst1, dst2, hg1, hg2,
      N, E, chunk, nbkt, nconvx);

  k_scan_block<<<dim3(nscb, 2), 256, 0, stream>>>(hg1, hg2, bs1, bs2, nsc);
  k_scan_sums<<<2, 512, 0, stream>>>(bs1, bs2, nscb);
  k_scan_add<<<dim3(nscb, 2), 256, 0, stream>>>(hg1, hg2, bs1, bs2, nsc);
  k_scat<<<dim3(NBLK, 2), 256, 0, stream>>>(src1, dst1, src2, dst2, hg1, hg2,
                                            bkt1, bkt2, E, chunk, nbkt);
  k_bcsr<<<dim3(nbkt, 2), 256, 0, stream>>>(hg1, hg2, bkt1, bkt2, csr1, csr2,
                                            rp1, rp2, E, N, nbkt);

  k_agg1<<<(N * 16 + 255) / 256, 256, 0, stream>>>(xcat, rp1, csr1, N);
  k_fused<<<(N + 63) / 64, 256, 0, stream>>>(xcat, w1f, b1, w2f, b2, out, p, N);
  k_agg2fin<<<(N * 10 + 255) / 256, 256, 0, stream>>>(p, rp2, csr2, out, N);
}